// Round 9
// baseline (234.581 us; speedup 1.0000x reference)
//
#include <hip/hip_runtime.h>
#include <stdint.h>

// AdaptiveSparsityLayer: LayerNorm (biased var, eps=1e-5) + top-K mask (K=409 of 4096)
// K1 skeleton (NT=256, one row/block, 5 fast-path barriers, wave0-scan, t0-select) with
// keys[16] ELIMINATED: keys are recomputed per sweep from xv (kept in regs) via a single
// deterministic sub/mul/fma helper -> live set ~50 VGPRs -> __launch_bounds__(256,8) is
// spill-free -> 8 blocks/CU so other blocks' load/store fills this block's selection
// bubble. gamma/beta re-reads per sweep are L2-resident broadcasts.

constexpr int FEATURES = 4096;
constexpr int KSEL     = 409;          // max(1, int(4096*0.1))
constexpr int NT       = 256;
constexpr int VPT      = FEATURES / NT / 4;   // 4 float4 per thread
constexpr int EPT      = FEATURES / NT;       // 16 elements per thread
constexpr float EPSF   = 1e-5f;
constexpr int NBINS    = 256;
constexpr int CAND_CAP = 64;

typedef float f32x4 __attribute__((ext_vector_type(4)));

__device__ __forceinline__ uint32_t key_of(float f) {
    uint32_t u = __float_as_uint(f);
    return (u & 0x80000000u) ? ~u : (u | 0x80000000u);  // ascending-order bijection
}
__device__ __forceinline__ float val_of(uint32_t k) {
    uint32_t u = (k & 0x80000000u) ? (k ^ 0x80000000u) : ~k;
    return __uint_as_float(u);
}
// Deterministic normalize+key: identical instruction sequence (sub, mul, fma) at every
// call site -> bit-identical keys across sweeps (required: selection vs mask coherence).
__device__ __forceinline__ uint32_t mkkey(float a, float gv, float bv,
                                          float mean, float rstd) {
    return key_of(__builtin_fmaf((a - mean) * rstd, gv, bv));
}

__global__ __launch_bounds__(NT, 8)
void lnk_kernel(const float* __restrict__ x, const float* __restrict__ g,
                const float* __restrict__ b, float* __restrict__ out)
{
    __shared__ float    s_f[8];
    __shared__ int      s_i[4];
    __shared__ uint32_t s_hist[NBINS];
    __shared__ uint32_t s_cand[CAND_CAP];
    __shared__ uint32_t s_n;
    __shared__ uint32_t s_T;
    __shared__ int      s_remK, s_above, s_keyhi, s_flag, s_doCut, s_needed;

    const int t    = threadIdx.x;
    const int lane = t & 63;
    const int wave = t >> 6;
    const int row  = blockIdx.x;

    s_hist[t] = 0u;
    if (t == 0) { s_n = 0u; s_flag = 0; s_doCut = 0; }

    const f32x4* xr = reinterpret_cast<const f32x4*>(x + (size_t)row * FEATURES);
    const f32x4* gr = reinterpret_cast<const f32x4*>(g);
    const f32x4* br = reinterpret_cast<const f32x4*>(b);

    // ---- load row + single-pass sum/sumsq ----
    f32x4 xv[VPT];
    float sum = 0.f, sq = 0.f;
    #pragma unroll
    for (int j = 0; j < VPT; ++j) {
        xv[j] = __builtin_nontemporal_load(&xr[j * NT + t]);
        sum += (xv[j].x + xv[j].y) + (xv[j].z + xv[j].w);
        sq  += (xv[j].x * xv[j].x + xv[j].y * xv[j].y)
             + (xv[j].z * xv[j].z + xv[j].w * xv[j].w);
    }
    #pragma unroll
    for (int o = 32; o; o >>= 1) { sum += __shfl_xor(sum, o); sq += __shfl_xor(sq, o); }
    if (lane == 0) { s_f[wave] = sum; s_f[4 + wave] = sq; }
    __syncthreads();                                               // B1
    const float mean = (s_f[0] + s_f[1] + s_f[2] + s_f[3]) * (1.0f / FEATURES);
    const float ex2  = (s_f[4] + s_f[5] + s_f[6] + s_f[7]) * (1.0f / FEATURES);
    const float var  = fmaxf(ex2 - mean * mean, 0.0f);
    const float rstd = rsqrtf(var + EPSF);

    // ---- sweep 1: keys on the fly -> integer-bin histogram over f in [1,2) ----
    int chi = 0;                      // count of f >= 2.0
    #pragma unroll
    for (int j = 0; j < VPT; ++j) {
        const f32x4 gv = gr[j * NT + t], bv = br[j * NT + t];
        #pragma unroll
        for (int k = 0; k < 4; ++k) {
            const uint32_t key = mkkey(xv[j][k], gv[k], bv[k], mean, rstd);
            const uint32_t e = key >> 23;     // positives: 256+exp; negatives < 256
            if (e >= 384u) ++chi;
            else if (e == 383u) atomicAdd(&s_hist[(key >> 15) & 255u], 1u);
        }
    }
    #pragma unroll
    for (int o = 32; o; o >>= 1) chi += __shfl_xor(chi, o);
    if (lane == 0) s_i[wave] = chi;
    __syncthreads();                                               // B2

    // ---- wave0: shuffle suffix scan + crossing-bin detect ----
    if (wave == 0) {
        const int cntHi = s_i[0] + s_i[1] + s_i[2] + s_i[3];
        const int R = KSEL - cntHi;           // rank to find below 2.0
        const int v0 = (int)s_hist[4 * lane + 0];
        const int v1 = (int)s_hist[4 * lane + 1];
        const int v2 = (int)s_hist[4 * lane + 2];
        const int v3 = (int)s_hist[4 * lane + 3];
        const int s3 = v3, s2 = v2 + s3, s1 = v1 + s2, s0 = v0 + s1;
        int suf = s0;
        #pragma unroll
        for (int o = 1; o < 64; o <<= 1) {
            const int u = __shfl_down(suf, o);
            suf += (lane + o < 64) ? u : 0;
        }
        const int excl = suf - s0;            // windowed count in bins >= 4*(lane+1)
        if (R >= 1) {
            const int bb[5] = { s0 + excl, s1 + excl, s2 + excl, s3 + excl, excl };
            #pragma unroll
            for (int i = 0; i < 4; ++i) {
                if (bb[i] >= R && R > bb[i + 1]) {     // exactly one (lane,i) block-wide
                    s_remK  = R - bb[i + 1];           // needed from crossing bin
                    s_above = cntHi + bb[i + 1];       // strictly above the bin
                    s_keyhi = (int)((0xBF800000u >> 15) + (uint32_t)(4 * lane + i));
                }
            }
            if (lane == 0 && suf < R) s_flag = 1;      // window miss (below 1.0)
        } else if (lane == 0) s_flag = 1;              // threshold >= 2.0
    }
    __syncthreads();                                               // B3

    int flag = s_flag;
    uint32_t T = 0u;
    int doCut = 0, needed = 0;

    // ---- sweep 2: gather crossing-bin candidates (17-bit match), t0 select ----
    if (!flag) {
        const uint32_t keyhi = (uint32_t)s_keyhi;
        #pragma unroll
        for (int j = 0; j < VPT; ++j) {
            const f32x4 gv = gr[j * NT + t], bv = br[j * NT + t];
            #pragma unroll
            for (int k = 0; k < 4; ++k) {
                const uint32_t key = mkkey(xv[j][k], gv[k], bv[k], mean, rstd);
                if ((key >> 15) == keyhi) {
                    const uint32_t p = atomicAdd(&s_n, 1u);
                    if (p < CAND_CAP) s_cand[p] = key;
                }
            }
        }
        __syncthreads();                                           // B4
        if (t == 0) {
            const int n = (int)s_n;
            if (n > CAND_CAP) s_flag = 1;
            else {
                const int remK = s_remK;
                uint32_t Tl = 0u; int gtT = 0, eqT = 0;
                for (int i2 = 0; i2 < n; ++i2) {
                    const uint32_t ki = s_cand[i2];
                    int gt = 0, eq = 0;
                    for (int j2 = 0; j2 < n; ++j2) {
                        gt += (s_cand[j2] > ki); eq += (s_cand[j2] == ki);
                    }
                    if (gt < remK && remK <= gt + eq) { Tl = ki; gtT = gt; eqT = eq; break; }
                }
                s_T = Tl;
                const int nd = KSEL - (s_above + gtT);   // all ==T keys are in this bin
                s_needed = nd;
                s_doCut  = (nd < eqT);
            }
        }
        __syncthreads();                                           // B5
        flag = s_flag;
        if (!flag) { T = s_T; doCut = s_doCut; needed = s_needed; }
    }

    // ---- exact fallback: 32-step bit bisection (rare) ----
    if (flag) {
        T = 0u;
        for (int bit = 31; bit >= 0; --bit) {
            const uint32_t candT = T | (1u << bit);
            int c = 0;
            #pragma unroll
            for (int j = 0; j < VPT; ++j) {
                const f32x4 gv = gr[j * NT + t], bv = br[j * NT + t];
                #pragma unroll
                for (int k = 0; k < 4; ++k)
                    c += (mkkey(xv[j][k], gv[k], bv[k], mean, rstd) >= candT);
            }
            #pragma unroll
            for (int o = 32; o; o >>= 1) c += __shfl_xor(c, o);
            __syncthreads();
            if (lane == 0) s_i[wave] = c;
            __syncthreads();
            c = s_i[0] + s_i[1] + s_i[2] + s_i[3];
            if (c >= KSEL) T = candT;        // block-uniform
        }
        int cg = 0, ce = 0;
        #pragma unroll
        for (int j = 0; j < VPT; ++j) {
            const f32x4 gv = gr[j * NT + t], bv = br[j * NT + t];
            #pragma unroll
            for (int k = 0; k < 4; ++k) {
                const uint32_t key = mkkey(xv[j][k], gv[k], bv[k], mean, rstd);
                cg += (key > T); ce += (key == T);
            }
        }
        int pk = (cg << 13) | ce;            // each total < 2^13
        #pragma unroll
        for (int o = 32; o; o >>= 1) pk += __shfl_xor(pk, o);
        __syncthreads();
        if (lane == 0) s_i[wave] = pk;
        __syncthreads();
        const int tot2  = s_i[0] + s_i[1] + s_i[2] + s_i[3];
        const int cntGt = tot2 >> 13, cntEq = tot2 & 8191;
        needed = KSEL - cntGt;
        doCut = (needed < cntEq);
    }

    // ---- rare: ties straddle boundary -> lowest-index cutoff ----
    int cutoff = FEATURES;
    if (doCut) {                             // block-uniform
        int lo2 = 0, hi2 = FEATURES;
        for (int it = 0; it < 12; ++it) {
            const int mid = (lo2 + hi2) >> 1;
            int cc = 0;
            #pragma unroll
            for (int j = 0; j < VPT; ++j) {
                const f32x4 gv = gr[j * NT + t], bv = br[j * NT + t];
                #pragma unroll
                for (int k = 0; k < 4; ++k) {
                    const uint32_t key = mkkey(xv[j][k], gv[k], bv[k], mean, rstd);
                    const int idx = 4 * (j * NT + t) + k;
                    cc += (key == T && idx < mid);
                }
            }
            #pragma unroll
            for (int o = 32; o; o >>= 1) cc += __shfl_xor(cc, o);
            __syncthreads();
            if (lane == 0) s_i[wave] = cc;
            __syncthreads();
            const int ccs = s_i[0] + s_i[1] + s_i[2] + s_i[3];
            if (ccs >= needed) hi2 = mid; else lo2 = mid;
        }
        cutoff = hi2;
    }

    // ---- sweep 3: recompute key -> sel ? xn : 0 (nontemporal store) ----
    f32x4* outr = reinterpret_cast<f32x4*>(out + (size_t)row * FEATURES);
    if (!doCut) {                            // block-uniform common case: sel = key >= T
        #pragma unroll
        for (int j = 0; j < VPT; ++j) {
            const f32x4 gv = gr[j * NT + t], bv = br[j * NT + t];
            f32x4 o4;
            #pragma unroll
            for (int k = 0; k < 4; ++k) {
                const uint32_t key = mkkey(xv[j][k], gv[k], bv[k], mean, rstd);
                o4[k] = (key >= T) ? val_of(key) : 0.0f;
            }
            __builtin_nontemporal_store(o4, &outr[j * NT + t]);
        }
    } else {
        #pragma unroll
        for (int j = 0; j < VPT; ++j) {
            const f32x4 gv = gr[j * NT + t], bv = br[j * NT + t];
            f32x4 o4;
            #pragma unroll
            for (int k = 0; k < 4; ++k) {
                const uint32_t key = mkkey(xv[j][k], gv[k], bv[k], mean, rstd);
                const int idx = 4 * (j * NT + t) + k;
                const bool sel = (key > T) || (key == T && idx < cutoff);
                o4[k] = sel ? val_of(key) : 0.0f;
            }
            __builtin_nontemporal_store(o4, &outr[j * NT + t]);
        }
    }
}

extern "C" void kernel_launch(void* const* d_in, const int* in_sizes, int n_in,
                              void* d_out, int out_size, void* d_ws, size_t ws_size,
                              hipStream_t stream) {
    const float* x = (const float*)d_in[0];
    const float* g = (const float*)d_in[1];
    const float* b = (const float*)d_in[2];
    float* out = (float*)d_out;
    const int batch = in_sizes[0] / FEATURES;
    hipLaunchKernelGGL(lnk_kernel, dim3(batch), dim3(NT), 0, stream, x, g, b, out);
}

// Round 10
// 98.747 us; speedup vs baseline: 2.3756x; 2.3756x over previous
//
#include <hip/hip_runtime.h>
#include <stdint.h>

// AdaptiveSparsityLayer: LayerNorm (biased var, eps=1e-5) + top-K mask (K=409 of 4096)
// FINAL: byte-exact K1 (R1, 98.9us) — the unbeaten configuration after 8 experiments.
// One block (256 threads) per row; row in registers; exact rank select via integer-bin
// histogram over f in [1,2) (bin = float bits), wave0 shuffle suffix-scan, t0 serial
// select; 5 fast-path barriers. Exact fallbacks: 32-step bit bisection (window miss),
// lowest-index tie cutoff (boundary ties). Nontemporal x loads / out stores.
// Tried and regressed: (256,8) bounds [R7 null, R2/R8 spill], reg/LDS pipelining
// [R5/R6], barrier restructure [R3], NT=512 [R4]. 86% of 6.29 TB/s copy ceiling;
// residual = barrier-serialized selection, structural at HIP level.

constexpr int FEATURES = 4096;
constexpr int KSEL     = 409;          // max(1, int(4096*0.1))
constexpr int NT       = 256;
constexpr int VPT      = FEATURES / NT / 4;   // 4 float4 per thread
constexpr int EPT      = FEATURES / NT;       // 16 elements per thread
constexpr float EPSF   = 1e-5f;
constexpr int NBINS    = 256;
constexpr int CAND_CAP = 64;

typedef float f32x4 __attribute__((ext_vector_type(4)));

__device__ __forceinline__ uint32_t key_of(float f) {
    uint32_t u = __float_as_uint(f);
    return (u & 0x80000000u) ? ~u : (u | 0x80000000u);  // ascending-order bijection
}
__device__ __forceinline__ float val_of(uint32_t k) {
    uint32_t u = (k & 0x80000000u) ? (k ^ 0x80000000u) : ~k;
    return __uint_as_float(u);
}

__global__ __launch_bounds__(NT)
void lnk_kernel(const float* __restrict__ x, const float* __restrict__ g,
                const float* __restrict__ b, float* __restrict__ out)
{
    __shared__ float    s_f[8];
    __shared__ int      s_i[8];
    __shared__ uint32_t s_hist[NBINS];
    __shared__ uint32_t s_cand[CAND_CAP];
    __shared__ uint32_t s_n;
    __shared__ uint32_t s_T;
    __shared__ int      s_binfo[2];   // [0]=remK within crossing bin, [1]=count strictly above bin
    __shared__ int      s_keyhi;     // key>>15 of crossing bin
    __shared__ int      s_flag;      // 1 -> exact bisection fallback
    __shared__ int      s_doCut;     // 1 -> tie straddles boundary

    const int t    = threadIdx.x;
    const int lane = t & 63;
    const int wave = t >> 6;
    const int row  = blockIdx.x;

    s_hist[t] = 0u;
    if (t == 0) { s_n = 0u; s_flag = 0; s_doCut = 0; }

    const f32x4* xr = reinterpret_cast<const f32x4*>(x + (size_t)row * FEATURES);
    const f32x4* gr = reinterpret_cast<const f32x4*>(g);
    const f32x4* br = reinterpret_cast<const f32x4*>(b);

    // ---- load row + single-pass sum/sumsq ----
    f32x4 xv[VPT];
    float sum = 0.f, sq = 0.f;
    #pragma unroll
    for (int j = 0; j < VPT; ++j) {
        xv[j] = __builtin_nontemporal_load(&xr[j * NT + t]);
        sum += (xv[j].x + xv[j].y) + (xv[j].z + xv[j].w);
        sq  += (xv[j].x * xv[j].x + xv[j].y * xv[j].y)
             + (xv[j].z * xv[j].z + xv[j].w * xv[j].w);
    }
    #pragma unroll
    for (int o = 32; o; o >>= 1) { sum += __shfl_xor(sum, o); sq += __shfl_xor(sq, o); }
    if (lane == 0) { s_f[wave] = sum; s_f[4 + wave] = sq; }
    __syncthreads();                                               // B1
    const float mean = (s_f[0] + s_f[1] + s_f[2] + s_f[3]) * (1.0f / FEATURES);
    const float ex2  = (s_f[4] + s_f[5] + s_f[6] + s_f[7]) * (1.0f / FEATURES);
    const float var  = fmaxf(ex2 - mean * mean, 0.0f);
    const float rstd = rsqrtf(var + EPSF);

    // ---- normalize -> order keys (xn recoverable bit-exactly) ----
    uint32_t keys[EPT];
    #pragma unroll
    for (int j = 0; j < VPT; ++j) {
        f32x4 gv = gr[j * NT + t], bv = br[j * NT + t];
        keys[4 * j + 0] = key_of((xv[j].x - mean) * rstd * gv.x + bv.x);
        keys[4 * j + 1] = key_of((xv[j].y - mean) * rstd * gv.y + bv.y);
        keys[4 * j + 2] = key_of((xv[j].z - mean) * rstd * gv.z + bv.z);
        keys[4 * j + 3] = key_of((xv[j].w - mean) * rstd * gv.w + bv.w);
    }

    // ---- integer-bin histogram over f in [1,2): key>>23==383, bin=(key>>15)&255 ----
    int chi = 0;   // count of f >= 2.0
    #pragma unroll
    for (int i = 0; i < EPT; ++i) {
        const uint32_t e = keys[i] >> 23;
        if (e >= 384u) ++chi;
        else if (e == 383u) atomicAdd(&s_hist[(keys[i] >> 15) & 255u], 1u);
    }
    #pragma unroll
    for (int o = 32; o; o >>= 1) chi += __shfl_xor(chi, o);
    if (lane == 0) s_i[wave] = chi;
    __syncthreads();                                               // B2

    // ---- wave0: barrier-free suffix scan + crossing-bin detect ----
    if (wave == 0) {
        const int cntHi = s_i[0] + s_i[1] + s_i[2] + s_i[3];
        const int R = KSEL - cntHi;            // rank to find below 2.0
        const int v0 = (int)s_hist[4 * lane + 0];
        const int v1 = (int)s_hist[4 * lane + 1];
        const int v2 = (int)s_hist[4 * lane + 2];
        const int v3 = (int)s_hist[4 * lane + 3];
        const int s3 = v3, s2 = v2 + s3, s1 = v1 + s2, s0 = v0 + s1;
        int suf = s0;
        #pragma unroll
        for (int o = 1; o < 64; o <<= 1) {
            const int u = __shfl_down(suf, o);
            suf += (lane + o < 64) ? u : 0;
        }
        const int excl = suf - s0;             // windowed elements in lanes > lane
        if (R >= 1) {
            const int bb[5] = { s0 + excl, s1 + excl, s2 + excl, s3 + excl, excl };
            #pragma unroll
            for (int i = 0; i < 4; ++i) {
                if (bb[i] >= R && R > bb[i + 1]) {     // exactly one (lane,i) block-wide
                    s_binfo[0] = R - bb[i + 1];        // remK inside crossing bin
                    s_binfo[1] = cntHi + bb[i + 1];    // total strictly above bin
                    s_keyhi    = (int)((0xBF800000u >> 15) + (uint32_t)(4 * lane + i));
                }
            }
            if (lane == 0 && bb[0] < R) s_flag = 1;    // window miss
        } else if (lane == 0) s_flag = 1;              // threshold >= 2.0
    }
    __syncthreads();                                               // B3

    // ---- fast path: gather crossing-bin candidates (17-bit key match) ----
    if (!s_flag) {
        const uint32_t keyhi = (uint32_t)s_keyhi;
        #pragma unroll
        for (int i = 0; i < EPT; ++i) {
            if ((keys[i] >> 15) == keyhi) {
                const uint32_t p = atomicAdd(&s_n, 1u);
                if (p < CAND_CAP) s_cand[p] = keys[i];
            }
        }
        __syncthreads();                                           // B4
        if (t == 0) {
            const int n = (int)s_n;
            if (n > CAND_CAP) s_flag = 1;
            else {
                const int remK = s_binfo[0];
                uint32_t T = 0u; int gtT = 0, eqT = 0;
                for (int i2 = 0; i2 < n; ++i2) {
                    const uint32_t ki = s_cand[i2];
                    int gt = 0, eq = 0;
                    for (int j2 = 0; j2 < n; ++j2) {
                        gt += (s_cand[j2] > ki); eq += (s_cand[j2] == ki);
                    }
                    if (gt < remK && remK <= gt + eq) { T = ki; gtT = gt; eqT = eq; break; }
                }
                s_T = T;
                const int needed = KSEL - (s_binfo[1] + gtT);   // all ==T keys are in this bin
                if (needed < eqT) { s_doCut = 1; s_i[4] = needed; }
            }
        }
        __syncthreads();                                           // B5
    }

    // ---- exact fallback: 32-step bit bisection (rare; arbitrary gamma/beta) ----
    if (s_flag) {
        uint32_t T = 0u;
        for (int bit = 31; bit >= 0; --bit) {
            const uint32_t candT = T | (1u << bit);
            int c = 0;
            #pragma unroll
            for (int i = 0; i < EPT; ++i) c += (keys[i] >= candT);
            #pragma unroll
            for (int o = 32; o; o >>= 1) c += __shfl_xor(c, o);
            __syncthreads();
            if (lane == 0) s_i[wave] = c;
            __syncthreads();
            c = s_i[0] + s_i[1] + s_i[2] + s_i[3];
            if (c >= KSEL) T = candT;                  // block-uniform
        }
        if (t == 0) s_T = T;
        int cg = 0, ce = 0;
        #pragma unroll
        for (int i = 0; i < EPT; ++i) { cg += (keys[i] > T); ce += (keys[i] == T); }
        int pk = (cg << 13) | ce;                      // totals < 2^13 each
        #pragma unroll
        for (int o = 32; o; o >>= 1) pk += __shfl_xor(pk, o);
        __syncthreads();
        if (lane == 0) s_i[wave] = pk;
        __syncthreads();
        if (t == 0) {
            const int tot2  = s_i[0] + s_i[1] + s_i[2] + s_i[3];
            const int cntGt = tot2 >> 13, cntEq = tot2 & 8191;
            const int needed = KSEL - cntGt;
            if (needed < cntEq) { s_doCut = 1; s_i[4] = needed; }
        }
        __syncthreads();
    }

    const uint32_t T = s_T;
    const int doCut = s_doCut;

    // ---- rare: ties straddle boundary -> lowest-index cutoff via binary search ----
    int cutoff = FEATURES;
    if (doCut) {                                       // block-uniform
        const int needed = s_i[4];
        int lo2 = 0, hi2 = FEATURES;
        for (int it = 0; it < 12; ++it) {
            const int mid = (lo2 + hi2) >> 1;
            int cc = 0;
            #pragma unroll
            for (int i = 0; i < EPT; ++i) {
                const int idx = 4 * ((i >> 2) * NT + t) + (i & 3);
                cc += (keys[i] == T && idx < mid);
            }
            #pragma unroll
            for (int o = 32; o; o >>= 1) cc += __shfl_xor(cc, o);
            __syncthreads();
            if (lane == 0) s_i[wave] = cc;
            __syncthreads();
            cc = s_i[0] + s_i[1] + s_i[2] + s_i[3];
            if (cc >= needed) hi2 = mid; else lo2 = mid;
        }
        cutoff = hi2;
    }

    // ---- write: sel ? xn : 0 (nontemporal) ----
    f32x4* outr = reinterpret_cast<f32x4*>(out + (size_t)row * FEATURES);
    #pragma unroll
    for (int j = 0; j < VPT; ++j) {
        f32x4 o4;
        #pragma unroll
        for (int k = 0; k < 4; ++k) {
            const uint32_t key = keys[4 * j + k];
            const int idx = 4 * (j * NT + t) + k;
            const bool sel = (key > T) || (key == T && (!doCut || idx < cutoff));
            o4[k] = sel ? val_of(key) : 0.0f;
        }
        __builtin_nontemporal_store(o4, &outr[j * NT + t]);
    }
}

extern "C" void kernel_launch(void* const* d_in, const int* in_sizes, int n_in,
                              void* d_out, int out_size, void* d_ws, size_t ws_size,
                              hipStream_t stream) {
    const float* x = (const float*)d_in[0];
    const float* g = (const float*)d_in[1];
    const float* b = (const float*)d_in[2];
    float* out = (float*)d_out;
    const int batch = in_sizes[0] / FEATURES;
    hipLaunchKernelGGL(lnk_kernel, dim3(batch), dim3(NT), 0, stream, x, g, b, out);
}